// Round 1
// baseline (3420.218 us; speedup 1.0000x reference)
//
#include <hip/hip_runtime.h>
#include <cfloat>
#include <cmath>

#define N 8192
#define D 512
#define K 16
#define BI 32
#define BJ 128
#define KT 64

// ---------------- kernel 1: row squared norms ----------------
__global__ __launch_bounds__(256)
void k_sqnorm(const float* __restrict__ emb, float* __restrict__ sq) {
    int row = blockIdx.x * 4 + (threadIdx.x >> 6);
    int lane = threadIdx.x & 63;
    const float4* e = (const float4*)(emb + (size_t)row * D);
    float s = 0.f;
    #pragma unroll
    for (int c = 0; c < 2; c++) {
        float4 v = e[lane + 64 * c];
        s += v.x * v.x + v.y * v.y + v.z * v.z + v.w * v.w;
    }
    for (int off = 32; off; off >>= 1) s += __shfl_down(s, off, 64);
    if (lane == 0) sq[row] = s;
}

// ---------------- kernel 2: fused distance GEMM + top-16 ----------------
// Block: 256 threads, handles BI=32 rows. Loops over all N cols in BJ=128 tiles.
// Thread (ti=t>>4, tj=t&15): rows {2ti, 2ti+1}, cols {tj+16m, m=0..7}.
__global__ __launch_bounds__(256, 1)
void k_knn(const float* __restrict__ emb, const float* __restrict__ sq,
           int* __restrict__ knn_idx, float* __restrict__ row_sum) {
    __shared__ float As[BI][D + 4];        // 66 KB, pad keeps ti-groups on distinct banks
    __shared__ float Bs[BJ][KT + 4];       // 34.8 KB, 2-way worst (free)
    __shared__ float svD[BI][BJ];          // survivor buffer (d2)
    __shared__ int   svI[BI][BJ];          // survivor buffer (idx)
    __shared__ int   scount[BI];
    __shared__ float listD[BI][K];
    __shared__ int   listI[BI][K];
    __shared__ float kmax[BI];

    const int t = threadIdx.x;
    const int ib = blockIdx.x * BI;

    // stage A rows (full depth) into LDS
    for (int s = t; s < BI * (D / 4); s += 256) {
        int r = s >> 7, c = s & 127;
        float4 v = ((const float4*)(emb + (size_t)(ib + r) * D))[c];
        *(float4*)&As[r][c * 4] = v;
    }
    if (t < BI) {
        scount[t] = 0;
        kmax[t] = FLT_MAX;
        #pragma unroll
        for (int q = 0; q < K; q++) { listD[t][q] = FLT_MAX; listI[t][q] = 0; }
    }
    __syncthreads();

    const int ti = t >> 4;
    const int tj = t & 15;
    const int i0 = ib + 2 * ti;
    const float sqi0 = sq[i0];
    const float sqi1 = sq[i0 + 1];

    for (int j0 = 0; j0 < N; j0 += BJ) {
        float acc0[8], acc1[8];
        #pragma unroll
        for (int m = 0; m < 8; m++) { acc0[m] = 0.f; acc1[m] = 0.f; }

        for (int k0 = 0; k0 < D; k0 += KT) {
            __syncthreads();   // previous tile's readers done before overwrite
            for (int s = t; s < BJ * (KT / 4); s += 256) {
                int r = s >> 4, c = s & 15;
                float4 v = ((const float4*)(emb + (size_t)(j0 + r) * D + k0))[c];
                *(float4*)&Bs[r][c * 4] = v;
            }
            __syncthreads();
            for (int k = 0; k < KT; k += 4) {
                float4 a0 = *(const float4*)&As[2 * ti][k0 + k];
                float4 a1 = *(const float4*)&As[2 * ti + 1][k0 + k];
                #pragma unroll
                for (int m = 0; m < 8; m++) {
                    float4 b = *(const float4*)&Bs[tj + 16 * m][k];
                    acc0[m] += a0.x * b.x; acc0[m] += a0.y * b.y;
                    acc0[m] += a0.z * b.z; acc0[m] += a0.w * b.w;
                    acc1[m] += a1.x * b.x; acc1[m] += a1.y * b.y;
                    acc1[m] += a1.z * b.z; acc1[m] += a1.w * b.w;
                }
            }
        }

        // filter candidates against current kth-smallest (stale-high => no false negatives)
        float km0 = kmax[2 * ti];
        float km1 = kmax[2 * ti + 1];
        #pragma unroll
        for (int m = 0; m < 8; m++) {
            int j = j0 + tj + 16 * m;
            float sj = sq[j];
            float d2 = sqi0 + sj - 2.f * acc0[m];
            if (d2 < km0 && j != i0) {
                int p = atomicAdd(&scount[2 * ti], 1);
                svD[2 * ti][p] = d2; svI[2 * ti][p] = j;
            }
            d2 = sqi1 + sj - 2.f * acc1[m];
            if (d2 < km1 && j != i0 + 1) {
                int p = atomicAdd(&scount[2 * ti + 1], 1);
                svD[2 * ti + 1][p] = d2; svI[2 * ti + 1][p] = j;
            }
        }
        __syncthreads();

        // serial per-row insertion of survivors (threads 0..31)
        if (t < BI) {
            int cnt = scount[t];
            float km = kmax[t];
            for (int p = 0; p < cnt; p++) {
                float d2 = svD[t][p];
                if (d2 < km) {
                    int am = 0; float mx = listD[t][0];
                    #pragma unroll
                    for (int q = 1; q < K; q++)
                        if (listD[t][q] > mx) { mx = listD[t][q]; am = q; }
                    listD[t][am] = d2; listI[t][am] = svI[t][p];
                    mx = listD[t][0];
                    #pragma unroll
                    for (int q = 1; q < K; q++) mx = fmaxf(mx, listD[t][q]);
                    km = mx;
                }
            }
            kmax[t] = km;
            scount[t] = 0;
        }
        __syncthreads();
    }

    if (t < BI) {
        float s = 0.f;
        #pragma unroll
        for (int q = 0; q < K; q++) {
            float d2 = listD[t][q];
            float dist = (d2 > 0.f) ? sqrtf(fmaxf(d2, 1e-12f)) : 0.f;
            s += dist;
            knn_idx[(size_t)(ib + t) * K + q] = listI[t][q];
        }
        row_sum[ib + t] = s;
    }
}

// ---------------- kernel 3: per-row curvature ----------------
__global__ __launch_bounds__(256)
void k_curv(const float* __restrict__ emb, const int* __restrict__ knn_idx,
            const float* __restrict__ row_sum, const float* __restrict__ ref_curv,
            float* __restrict__ curv_err) {
    __shared__ float nb[K][D + 4];
    __shared__ float dots[K][K];
    const int i = blockIdx.x;
    const int t = threadIdx.x;

    for (int s = t; s < K * (D / 4); s += 256) {
        int r = s >> 7, c = s & 127;
        int nidx = knn_idx[(size_t)i * K + r];
        float4 v = ((const float4*)(emb + (size_t)nidx * D))[c];
        *(float4*)&nb[r][c * 4] = v;
    }
    __syncthreads();

    if (t < 136) {                 // pairs (j <= l), includes diagonal (norms)
        int j = 0, rem = t;
        while (rem >= K - j) { rem -= K - j; j++; }
        int l = j + rem;
        float s = 0.f;
        for (int c = 0; c < D; c += 4) {
            float4 a = *(const float4*)&nb[j][c];
            float4 b = *(const float4*)&nb[l][c];
            s += a.x * b.x + a.y * b.y + a.z * b.z + a.w * b.w;
        }
        dots[j][l] = s;
    }
    __syncthreads();

    if (t == 0) {
        float sum = 0.f;
        for (int j = 0; j < K; j++)
            for (int l = j + 1; l < K; l++) {
                float d2 = dots[j][j] + dots[l][l] - 2.f * dots[j][l];
                sum += (d2 > 0.f) ? sqrtf(fmaxf(d2, 1e-12f)) : 0.f;
            }
        float inter_mean = sum / 120.f;
        float avg = row_sum[i] / 16.f;
        float curv = inter_mean / (avg + 1e-8f);
        float diff = curv - ref_curv[i];
        curv_err[i] = diff * diff;
    }
}

// ---------------- kernel 4: final scalar reduce ----------------
__global__ __launch_bounds__(1024)
void k_final(const float* __restrict__ curv_err, const float* __restrict__ row_sum,
             const float* __restrict__ ref_dist, float* __restrict__ out) {
    const int t = threadIdx.x;
    float s1 = 0.f, s2 = 0.f, s3 = 0.f;
    for (int i = t; i < N; i += 1024) { s1 += curv_err[i]; s2 += row_sum[i]; }
    for (int i = t; i < N * K; i += 1024) s3 += ref_dist[i];
    for (int off = 32; off; off >>= 1) {
        s1 += __shfl_down(s1, off, 64);
        s2 += __shfl_down(s2, off, 64);
        s3 += __shfl_down(s3, off, 64);
    }
    __shared__ float a1[16], a2[16], a3[16];
    int w = t >> 6, lane = t & 63;
    if (lane == 0) { a1[w] = s1; a2[w] = s2; a3[w] = s3; }
    __syncthreads();
    if (t == 0) {
        float t1 = 0.f, t2 = 0.f, t3 = 0.f;
        for (int q = 0; q < 16; q++) { t1 += a1[q]; t2 += a2[q]; t3 += a3[q]; }
        float curv_loss = t1 / (float)N;
        float dm = t2 / (float)(N * K);
        float rm = t3 / (float)(N * K);
        float d = dm - rm;
        out[0] = curv_loss + 0.1f * d * d;
    }
}

extern "C" void kernel_launch(void* const* d_in, const int* in_sizes, int n_in,
                              void* d_out, int out_size, void* d_ws, size_t ws_size,
                              hipStream_t stream) {
    const float* emb      = (const float*)d_in[0];
    const float* ref_curv = (const float*)d_in[1];
    const float* ref_dist = (const float*)d_in[2];
    float* out = (float*)d_out;

    float* sq       = (float*)d_ws;       // N
    float* row_sum  = sq + N;             // N
    float* curv_err = row_sum + N;        // N
    int*   knn      = (int*)(curv_err + N); // N*K

    k_sqnorm<<<N / 4, 256, 0, stream>>>(emb, sq);
    k_knn<<<N / BI, 256, 0, stream>>>(emb, sq, knn, row_sum);
    k_curv<<<N, 256, 0, stream>>>(emb, knn, row_sum, ref_curv, curv_err);
    k_final<<<1, 1024, 0, stream>>>(curv_err, row_sum, ref_dist, out);
}

// Round 2
// 681.377 us; speedup vs baseline: 5.0196x; 5.0196x over previous
//
#include <hip/hip_runtime.h>
#include <cfloat>
#include <cmath>
#include <stdint.h>

#define N 8192
#define D 512
#define K 16
#define RB 128     // rows per k_knn block
#define JS 2048    // cols per slice (4 slices)
#define JT 128     // j-tile width
#define KC 64      // k chunk
#define NCH (D / KC)
#define CAP 32     // survivor slots per row per pass

typedef __bf16 bf16x8 __attribute__((ext_vector_type(8)));
typedef __bf16 bf16x4 __attribute__((ext_vector_type(4)));
typedef float  f32x16 __attribute__((ext_vector_type(16)));

// ---------------- kernel 1: cast to bf16 + row squared norms (fp32) ----------
__global__ __launch_bounds__(256)
void k_cast_sqnorm(const float* __restrict__ emb, float* __restrict__ sq,
                   __bf16* __restrict__ embh) {
    int row = blockIdx.x * 4 + (threadIdx.x >> 6);
    int lane = threadIdx.x & 63;
    const float4* e = (const float4*)(emb + (size_t)row * D);
    float s = 0.f;
    #pragma unroll
    for (int c = 0; c < 2; c++) {
        float4 v = e[lane + 64 * c];
        s += v.x * v.x + v.y * v.y + v.z * v.z + v.w * v.w;
        bf16x4 h = { (__bf16)v.x, (__bf16)v.y, (__bf16)v.z, (__bf16)v.w };
        *(bf16x4*)&embh[(size_t)row * D + (size_t)(lane + 64 * c) * 4] = h;
    }
    for (int off = 32; off; off >>= 1) s += __shfl_down(s, off, 64);
    if (lane == 0) sq[row] = s;
}

// ---------------- kernel 2: MFMA distance GEMM + streaming top-16 ------------
// grid 256: rg = bid>>2 (128 rows), sl = bid&3 (2048-col slice).
// 4 waves, wave tile 64x64 = 4 x mfma_32x32x16_bf16 accumulators.
__global__ __launch_bounds__(256, 1)
void k_knn(const __bf16* __restrict__ embh, const float* __restrict__ sq,
           float* __restrict__ pd2, int* __restrict__ pidx) {
    __shared__ __align__(16) __bf16 As[RB][KC + 8];
    __shared__ __align__(16) __bf16 Bs[JT][KC + 8];
    __shared__ float svD[RB][CAP];
    __shared__ int   svI[RB][CAP];
    __shared__ float listD[RB][K];
    __shared__ int   listI[RB][K];
    __shared__ float sqr[RB];
    __shared__ float kadj[RB];    // kmax - sq[row]  (filter threshold on sqj-2*dot)
    __shared__ float kmaxA[RB];
    __shared__ int   scount[RB];
    __shared__ int   again;

    const int t   = threadIdx.x;
    const int rg  = blockIdx.x >> 2;
    const int sl  = blockIdx.x & 3;
    const int ib  = rg * RB;
    const int jsb = sl * JS;
    const int lane = t & 63, quad = lane >> 5, l31 = lane & 31;
    const int w  = t >> 6;
    const int wr = (w >> 1) * 64;
    const int wc = (w & 1) * 64;

    if (t < RB) {
        sqr[t] = sq[ib + t];
        kadj[t] = FLT_MAX; kmaxA[t] = FLT_MAX; scount[t] = 0;
        #pragma unroll
        for (int q = 0; q < K; q++) { listD[t][q] = FLT_MAX; listI[t][q] = 0; }
    }
    __syncthreads();

    for (int jt = 0; jt < JS / JT; jt++) {
        const int jb = jsb + jt * JT;
        f32x16 zero = {};
        f32x16 acc[2][2];
        acc[0][0] = zero; acc[0][1] = zero; acc[1][0] = zero; acc[1][1] = zero;

        // stage chunk 0
        #pragma unroll
        for (int q = 0; q < 4; q++) {
            int s = t + 256 * q;           // 0..1023
            int row = s >> 3, g = s & 7;   // 128 rows x 8 granules of 8 bf16
            *(uint4*)&As[row][g * 8] = *(const uint4*)&embh[(size_t)(ib + row) * D + g * 8];
            *(uint4*)&Bs[row][g * 8] = *(const uint4*)&embh[(size_t)(jb + row) * D + g * 8];
        }
        __syncthreads();

        uint4 pfA[4], pfB[4];
        for (int kc = 0; kc < NCH; kc++) {
            if (kc + 1 < NCH) {            // register prefetch of next chunk
                int k0 = (kc + 1) * KC;
                #pragma unroll
                for (int q = 0; q < 4; q++) {
                    int s = t + 256 * q; int row = s >> 3, g = s & 7;
                    pfA[q] = *(const uint4*)&embh[(size_t)(ib + row) * D + k0 + g * 8];
                    pfB[q] = *(const uint4*)&embh[(size_t)(jb + row) * D + k0 + g * 8];
                }
            }
            #pragma unroll
            for (int kk = 0; kk < KC / 16; kk++) {
                int ko = kk * 16 + quad * 8;
                bf16x8 a0 = *(const bf16x8*)&As[wr + l31][ko];
                bf16x8 a1 = *(const bf16x8*)&As[wr + 32 + l31][ko];
                bf16x8 b0 = *(const bf16x8*)&Bs[wc + l31][ko];
                bf16x8 b1 = *(const bf16x8*)&Bs[wc + 32 + l31][ko];
                acc[0][0] = __builtin_amdgcn_mfma_f32_32x32x16_bf16(a0, b0, acc[0][0], 0, 0, 0);
                acc[0][1] = __builtin_amdgcn_mfma_f32_32x32x16_bf16(a0, b1, acc[0][1], 0, 0, 0);
                acc[1][0] = __builtin_amdgcn_mfma_f32_32x32x16_bf16(a1, b0, acc[1][0], 0, 0, 0);
                acc[1][1] = __builtin_amdgcn_mfma_f32_32x32x16_bf16(a1, b1, acc[1][1], 0, 0, 0);
            }
            __syncthreads();               // all waves done reading As/Bs
            if (kc + 1 < NCH) {
                #pragma unroll
                for (int q = 0; q < 4; q++) {
                    int s = t + 256 * q; int row = s >> 3, g = s & 7;
                    *(uint4*)&As[row][g * 8] = pfA[q];
                    *(uint4*)&Bs[row][g * 8] = pfB[q];
                }
            }
            __syncthreads();               // next chunk visible
        }

        // ---- selection: capped survivor buffer + dedupe mask + retry ----
        float sqc0 = sq[jb + wc + l31];
        float sqc1 = sq[jb + wc + 32 + l31];
        uint64_t mask = 0;
        while (true) {
            if (t == 0) again = 0;
            #pragma unroll
            for (int r = 0; r < 2; r++)
            #pragma unroll
            for (int c = 0; c < 2; c++)
            #pragma unroll
            for (int reg = 0; reg < 16; reg++) {
                int bit = ((r * 2 + c) << 4) | reg;
                if ((mask >> bit) & 1) continue;
                int row_l = wr + r * 32 + ((reg & 3) + ((reg >> 2) << 3) + (quad << 2));
                float t2 = (c ? sqc1 : sqc0) - 2.f * acc[r][c][reg];
                if (t2 < kadj[row_l]) {
                    int j = jb + wc + c * 32 + l31;
                    if (j != ib + row_l) {
                        int p = atomicAdd(&scount[row_l], 1);
                        if (p < CAP) {
                            svD[row_l][p] = t2 + sqr[row_l];
                            svI[row_l][p] = j;
                            mask |= (1ull << bit);
                        }
                    }
                }
            }
            __syncthreads();
            if (t < RB) {
                int cnt = scount[t];
                if (cnt) {
                    int m = cnt < CAP ? cnt : CAP;
                    float kmx = kmaxA[t];
                    for (int p = 0; p < m; p++) {
                        float d2 = svD[t][p];
                        if (d2 < kmx) {
                            int am = 0; float mx = listD[t][0];
                            #pragma unroll
                            for (int q = 1; q < K; q++)
                                if (listD[t][q] > mx) { mx = listD[t][q]; am = q; }
                            listD[t][am] = d2; listI[t][am] = svI[t][p];
                            mx = listD[t][0];
                            #pragma unroll
                            for (int q = 1; q < K; q++) mx = fmaxf(mx, listD[t][q]);
                            kmx = mx;
                        }
                    }
                    kmaxA[t] = kmx; kadj[t] = kmx - sqr[t];
                    scount[t] = 0;
                    if (cnt > CAP) again = 1;
                }
            }
            __syncthreads();
            int more = again;
            __syncthreads();
            if (!more) break;
        }
    }

    if (t < RB) {
        #pragma unroll
        for (int q = 0; q < K; q++) {
            pd2[(size_t)(ib + t) * 64 + sl * K + q]  = listD[t][q];
            pidx[(size_t)(ib + t) * 64 + sl * K + q] = listI[t][q];
        }
    }
}

// ---------------- kernel 3: merge 4 partial lists per row --------------------
__global__ __launch_bounds__(256)
void k_merge(const float* __restrict__ pd2, const int* __restrict__ pidx,
             int* __restrict__ knn, float* __restrict__ row_sum) {
    int row = blockIdx.x * 256 + threadIdx.x;
    float bd[K]; int bi[K];
    #pragma unroll
    for (int q = 0; q < K; q++) { bd[q] = FLT_MAX; bi[q] = 0; }
    float kmx = FLT_MAX;
    const float* pr = pd2 + (size_t)row * 64;
    const int*   pi = pidx + (size_t)row * 64;
    for (int s = 0; s < 64; s++) {
        float d2 = pr[s];
        if (d2 < kmx) {
            int am = 0; float mx = bd[0];
            #pragma unroll
            for (int q = 1; q < K; q++) if (bd[q] > mx) { mx = bd[q]; am = q; }
            bd[am] = d2; bi[am] = pi[s];
            mx = bd[0];
            #pragma unroll
            for (int q = 1; q < K; q++) mx = fmaxf(mx, bd[q]);
            kmx = mx;
        }
    }
    float s = 0.f;
    #pragma unroll
    for (int q = 0; q < K; q++) {
        float d2 = bd[q];
        s += (d2 > 0.f) ? sqrtf(fmaxf(d2, 1e-12f)) : 0.f;
        knn[(size_t)row * K + q] = bi[q];
    }
    row_sum[row] = s;
}

// ---------------- kernel 4: per-row curvature (fp32) -------------------------
__global__ __launch_bounds__(256)
void k_curv(const float* __restrict__ emb, const int* __restrict__ knn_idx,
            const float* __restrict__ row_sum, const float* __restrict__ ref_curv,
            float* __restrict__ curv_err) {
    __shared__ float nb[K][D + 4];
    __shared__ float dots[K][K];
    const int i = blockIdx.x;
    const int t = threadIdx.x;

    for (int s = t; s < K * (D / 4); s += 256) {
        int r = s >> 7, c = s & 127;
        int nidx = knn_idx[(size_t)i * K + r];
        float4 v = ((const float4*)(emb + (size_t)nidx * D))[c];
        *(float4*)&nb[r][c * 4] = v;
    }
    __syncthreads();

    if (t < 136) {
        int j = 0, rem = t;
        while (rem >= K - j) { rem -= K - j; j++; }
        int l = j + rem;
        float s = 0.f;
        for (int c = 0; c < D; c += 4) {
            float4 a = *(const float4*)&nb[j][c];
            float4 b = *(const float4*)&nb[l][c];
            s += a.x * b.x + a.y * b.y + a.z * b.z + a.w * b.w;
        }
        dots[j][l] = s;
    }
    __syncthreads();

    if (t == 0) {
        float sum = 0.f;
        for (int j = 0; j < K; j++)
            for (int l = j + 1; l < K; l++) {
                float d2 = dots[j][j] + dots[l][l] - 2.f * dots[j][l];
                sum += (d2 > 0.f) ? sqrtf(fmaxf(d2, 1e-12f)) : 0.f;
            }
        float inter_mean = sum / 120.f;
        float avg = row_sum[i] / 16.f;
        float curv = inter_mean / (avg + 1e-8f);
        float diff = curv - ref_curv[i];
        curv_err[i] = diff * diff;
    }
}

// ---------------- kernel 5: final scalar reduce ------------------------------
__global__ __launch_bounds__(1024)
void k_final(const float* __restrict__ curv_err, const float* __restrict__ row_sum,
             const float* __restrict__ ref_dist, float* __restrict__ out) {
    const int t = threadIdx.x;
    float s1 = 0.f, s2 = 0.f, s3 = 0.f;
    for (int i = t; i < N; i += 1024) { s1 += curv_err[i]; s2 += row_sum[i]; }
    for (int i = t; i < N * K; i += 1024) s3 += ref_dist[i];
    for (int off = 32; off; off >>= 1) {
        s1 += __shfl_down(s1, off, 64);
        s2 += __shfl_down(s2, off, 64);
        s3 += __shfl_down(s3, off, 64);
    }
    __shared__ float a1[16], a2[16], a3[16];
    int w = t >> 6, lane = t & 63;
    if (lane == 0) { a1[w] = s1; a2[w] = s2; a3[w] = s3; }
    __syncthreads();
    if (t == 0) {
        float t1 = 0.f, t2 = 0.f, t3 = 0.f;
        for (int q = 0; q < 16; q++) { t1 += a1[q]; t2 += a2[q]; t3 += a3[q]; }
        float curv_loss = t1 / (float)N;
        float dm = t2 / (float)(N * K);
        float rm = t3 / (float)(N * K);
        float d = dm - rm;
        out[0] = curv_loss + 0.1f * d * d;
    }
}

extern "C" void kernel_launch(void* const* d_in, const int* in_sizes, int n_in,
                              void* d_out, int out_size, void* d_ws, size_t ws_size,
                              hipStream_t stream) {
    const float* emb      = (const float*)d_in[0];
    const float* ref_curv = (const float*)d_in[1];
    const float* ref_dist = (const float*)d_in[2];
    float* out = (float*)d_out;

    float*  sq       = (float*)d_ws;                    // N
    float*  row_sum  = sq + N;                          // N
    float*  curv_err = row_sum + N;                     // N
    float*  pd2      = curv_err + N;                    // N*64
    int*    pidx     = (int*)(pd2 + (size_t)N * 64);    // N*64
    int*    knn      = pidx + (size_t)N * 64;           // N*K
    __bf16* embh     = (__bf16*)(knn + (size_t)N * K);  // N*D bf16 (8 MB)

    k_cast_sqnorm<<<N / 4, 256, 0, stream>>>(emb, sq, embh);
    k_knn<<<256, 256, 0, stream>>>(embh, sq, pd2, pidx);
    k_merge<<<N / 256, 256, 0, stream>>>(pd2, pidx, knn, row_sum);
    k_curv<<<N, 256, 0, stream>>>(emb, knn, row_sum, ref_curv, curv_err);
    k_final<<<1, 1024, 0, stream>>>(curv_err, row_sum, ref_dist, out);
}